// Round 1
// baseline (1341.896 us; speedup 1.0000x reference)
//
#include <hip/hip_runtime.h>
#include <math.h>

#define T_ 8
#define H_ 128
#define W_ 128
#define C_ 32
#define PS 8
#define STRIDE 4
#define HEADS 2
#define HD 16
#define L_ 64
#define NH 32
#define NW 32
#define NWIN (T_*NH*NW)
#define CP 33   // +1 pad: 2-way max LDS bank aliasing (free on CDNA4)

__global__ __launch_bounds__(128) void win_attn(
    const float* __restrict__ x,
    const float* __restrict__ qkv_w,
    const float* __restrict__ qkv_b,
    const float* __restrict__ rel_tab,
    const float* __restrict__ proj_w,
    const float* __restrict__ proj_b,
    const int*   __restrict__ rel_idx,
    float* __restrict__ out)
{
    __shared__ float sX[L_][CP];        // patch, reused as attn-out
    __shared__ float sW[3*C_][CP];      // qkv weights
    __shared__ float sK[L_][CP];
    __shared__ float sV[L_][CP];
    __shared__ float sTab[(2*PS-1)*(2*PS-1)*HEADS]; // 450 floats

    const int tid = threadIdx.x;
    const int wid = blockIdx.x;
    const int t_i = wid >> 10;
    const int rem = wid & 1023;
    const int wi  = rem >> 5;
    const int wj  = rem & 31;

    // stage qkv weights: 3072 floats
    for (int e = tid; e < 3*C_*C_; e += 128) {
        sW[e >> 5][e & 31] = qkv_w[e];
    }
    for (int e = tid; e < (2*PS-1)*(2*PS-1)*HEADS; e += 128) sTab[e] = rel_tab[e];

    // stage patch with reflected indexing: 64 tokens x 32 ch
    for (int e = tid; e < L_*C_; e += 128) {
        int tok = e >> 5, ch = e & 31;
        int pr = tok >> 3, pc = tok & 7;
        int ar = wi*STRIDE + pr; if (ar >= H_) ar = 2*(H_-1) - ar;
        int ac = wj*STRIDE + pc; if (ac >= W_) ac = 2*(W_-1) - ac;
        sX[tok][ch] = x[(((t_i*H_) + ar)*W_ + ac)*C_ + ch];
    }
    __syncthreads();

    const int h = tid >> 6;     // head (0..1), one wave per head
    const int l = tid & 63;     // token/row
    const float scale = 0.25f;  // HD^-0.5

    // q row into registers (bias then scale)
    float qr[HD];
    #pragma unroll
    for (int d = 0; d < HD; ++d) {
        float a = qkv_b[h*HD + d];
        #pragma unroll
        for (int ch = 0; ch < C_; ++ch) a += sX[l][ch] * sW[h*HD + d][ch];
        qr[d] = a * scale;
    }

    // K and V tiles: 2*64*32 outputs / 128 threads = 32 each
    for (int it = 0; it < 32; ++it) {
        int idx = it*128 + tid;       // 0..4095
        int mm  = idx >> 5;           // 0..127 (<64 => K, else V)
        int ch  = idx & 31;
        int tok = mm & 63;
        int wrow = (mm < 64 ? C_ : 2*C_) + ch;
        float a = qkv_b[wrow];
        #pragma unroll
        for (int c2 = 0; c2 < C_; ++c2) a += sX[tok][c2] * sW[wrow][c2];
        if (mm < 64) sK[tok][ch] = a; else sV[tok][ch] = a;
    }
    __syncthreads();

    // scores: bias first (int4 index loads), then q.k
    float s[L_];
    const int* irow = rel_idx + l*L_;
    #pragma unroll
    for (int m4 = 0; m4 < L_; m4 += 4) {
        int4 iv = *reinterpret_cast<const int4*>(irow + m4);
        s[m4+0] = sTab[iv.x*HEADS + h];
        s[m4+1] = sTab[iv.y*HEADS + h];
        s[m4+2] = sTab[iv.z*HEADS + h];
        s[m4+3] = sTab[iv.w*HEADS + h];
    }
    float smax = -1e30f;
    #pragma unroll
    for (int m = 0; m < L_; ++m) {
        float a = s[m];
        #pragma unroll
        for (int d = 0; d < HD; ++d) a += qr[d] * sK[m][h*HD + d];
        s[m] = a;
        smax = fmaxf(smax, a);
    }
    float ssum = 0.f;
    #pragma unroll
    for (int m = 0; m < L_; ++m) { float e = __expf(s[m] - smax); s[m] = e; ssum += e; }
    float inv = 1.f / ssum;

    float o[HD];
    #pragma unroll
    for (int d = 0; d < HD; ++d) o[d] = 0.f;
    #pragma unroll
    for (int m = 0; m < L_; ++m) {
        float p = s[m];
        #pragma unroll
        for (int d = 0; d < HD; ++d) o[d] += p * sV[m][h*HD + d];
    }

    // write attention output into sX (phase-2 reads of sX completed at last barrier)
    #pragma unroll
    for (int d = 0; d < HD; ++d) sX[l][h*HD + d] = o[d] * inv;
    __syncthreads();

    // proj + scatter-add (co uniform per wave -> broadcast proj_w reads)
    for (int it = 0; it < 16; ++it) {
        int idx = it*128 + tid;
        int co  = idx >> 6;       // 0..31
        int tok = idx & 63;
        float a = proj_b[co];
        #pragma unroll
        for (int ci = 0; ci < C_; ++ci) a += sX[tok][ci] * proj_w[co*C_ + ci];
        int pr = tok >> 3, pc = tok & 7;
        int ar = wi*STRIDE + pr; if (ar >= H_) ar = 2*(H_-1) - ar;
        int ac = wj*STRIDE + pc; if (ac >= W_) ac = 2*(W_-1) - ac;
        atomicAdd(out + ((((t_i*H_) + ar)*W_ + ac)*C_ + co), a);
    }
}

// divide by coverage count; cnt(r,c) = cr(r)*cc(c) (row/col factorize, incl. reflection)
__global__ __launch_bounds__(256) void div_kernel(float* __restrict__ out)
{
    int gid = blockIdx.x*blockDim.x + threadIdx.x;   // one float4 each
    const int total4 = T_*H_*W_*C_/4;
    if (gid >= total4) return;
    int pix = gid >> 3;              // 32 ch = 8 float4
    int c_ = pix % W_;
    int r_ = (pix / W_) % H_;
    int cr = 0, cc = 0;
    for (int i = 0; i < NH; ++i) {
        #pragma unroll
        for (int p = 0; p < PS; ++p) {
            int rr = i*STRIDE + p; if (rr >= H_) rr = 2*(H_-1) - rr;
            cr += (rr == r_);
            int aa = i*STRIDE + p; if (aa >= W_) aa = 2*(W_-1) - aa;
            cc += (aa == c_);
        }
    }
    float inv = 1.f / ((float)cr*(float)cc + 1e-10f);
    float4* p4 = reinterpret_cast<float4*>(out) + gid;
    float4 v = *p4;
    v.x *= inv; v.y *= inv; v.z *= inv; v.w *= inv;
    *p4 = v;
}

extern "C" void kernel_launch(void* const* d_in, const int* in_sizes, int n_in,
                              void* d_out, int out_size, void* d_ws, size_t ws_size,
                              hipStream_t stream) {
    const float* x       = (const float*)d_in[0];
    const float* qkv_w   = (const float*)d_in[1];
    const float* qkv_b   = (const float*)d_in[2];
    const float* rel_tab = (const float*)d_in[3];
    const float* proj_w  = (const float*)d_in[4];
    const float* proj_b  = (const float*)d_in[5];
    const int*   rel_idx = (const int*)d_in[6];
    float* out = (float*)d_out;

    hipMemsetAsync(out, 0, (size_t)out_size*sizeof(float), stream);
    win_attn<<<NWIN, 128, 0, stream>>>(x, qkv_w, qkv_b, rel_tab, proj_w, proj_b, rel_idx, out);
    const int tot4 = T_*H_*W_*C_/4;
    div_kernel<<<(tot4 + 255)/256, 256, 0, stream>>>(out);
}

// Round 2
// 140.770 us; speedup vs baseline: 9.5326x; 9.5326x over previous
//
#include <hip/hip_runtime.h>
#include <stdint.h>

#define T_ 8
#define HH 128
#define WW 128
#define NWIN 8192

typedef __attribute__((ext_vector_type(8))) short bf16x8;
typedef __attribute__((ext_vector_type(4))) float f32x4;

// per-wave LDS region map (bytes), wave base = wv*PW
#define PW   26112
#define XO   0        /* sX   [64][40] bf16 stride 80B ; later sP [64][40] */
#define QO   5120     /* sQ[h] [64][24] stride 48B (+h*3072), elems 16..23 zeroed */
#define KO   11264    /* sK[h] [64][40] stride 80B (+h*5120), elems 16..31 zeroed ; h0 region reused as sO */
#define VO   21504    /* sVT[h] [16][72] stride 144B (+h*2304) */
#define OO   11264    /* sO [64][40] overlays sK h0 */
// shared (per block)
#define SWO  52224    /* Wqkv [96][40] */
#define SPO  59904    /* Wproj [32][40] */
#define STO  62464    /* packed bias table, 225 x u32 */
#define SMEM 63376

__device__ __forceinline__ uint16_t f2bf(float f) {
    union { float f; uint32_t u; } c; c.f = f;
    uint32_t u = c.u;
    u += 0x7fffu + ((u >> 16) & 1u);
    return (uint16_t)(u >> 16);
}
__device__ __forceinline__ float bf2f(uint16_t h) {
    union { uint32_t u; float f; } c; c.u = ((uint32_t)h) << 16;
    return c.f;
}

template<int WSPATH>
__global__ __launch_bounds__(128) void win_attn(
    const float* __restrict__ x, const float* __restrict__ qkv_w,
    const float* __restrict__ qkv_b, const float* __restrict__ rel_tab,
    const float* __restrict__ proj_w, const float* __restrict__ proj_b,
    const int* __restrict__ rel_idx, uint16_t* __restrict__ ws,
    float* __restrict__ out)
{
    __shared__ __align__(16) char smem[SMEM];
    const int tid = threadIdx.x;

    // ---- block-shared staging: weights (bf16) + packed bias table ----
    for (int i = tid; i < 768; i += 128) {                 // qkv_w: 96x32 f32 = 768 float4
        float4 v = reinterpret_cast<const float4*>(qkv_w)[i];
        int row = i >> 3, qf = i & 7;
        ushort4 o; o.x = f2bf(v.x); o.y = f2bf(v.y); o.z = f2bf(v.z); o.w = f2bf(v.w);
        *reinterpret_cast<ushort4*>(smem + SWO + row*80 + qf*8) = o;
    }
    for (int i = tid; i < 256; i += 128) {                 // proj_w: 32x32 = 256 float4
        float4 v = reinterpret_cast<const float4*>(proj_w)[i];
        int row = i >> 3, qf = i & 7;
        ushort4 o; o.x = f2bf(v.x); o.y = f2bf(v.y); o.z = f2bf(v.z); o.w = f2bf(v.w);
        *reinterpret_cast<ushort4*>(smem + SPO + row*80 + qf*8) = o;
    }
    for (int i = tid; i < 225; i += 128) {                 // rel table packed (h0|h1)
        uint32_t lo = f2bf(rel_tab[2*i]);
        uint32_t hi = f2bf(rel_tab[2*i + 1]);
        *reinterpret_cast<uint32_t*>(smem + STO + i*4) = lo | (hi << 16);
    }
    __syncthreads();   // only barrier: shared weights ready; everything below is wave-private

    const int wv = tid >> 6, lane = tid & 63;
    const int g = lane >> 4, ln = lane & 15;
    const int wid = blockIdx.x * 2 + wv;
    const int t_i = wid >> 10, wi = (wid >> 5) & 31, wj = wid & 31;
    char* wb = smem + wv * PW;

    // ---- zero the K-padding of Q (elems 16..23) and K (elems 16..31): NaN-safe zero*zero ----
    {
        uint4 z; z.x = 0; z.y = 0; z.z = 0; z.w = 0;
        *reinterpret_cast<uint4*>(wb + QO +        lane*48 + 32) = z;
        *reinterpret_cast<uint4*>(wb + QO + 3072 + lane*48 + 32) = z;
        *reinterpret_cast<uint4*>(wb + KO +        lane*80 + 32) = z;
        *reinterpret_cast<uint4*>(wb + KO +        lane*80 + 48) = z;
        *reinterpret_cast<uint4*>(wb + KO + 5120 + lane*80 + 32) = z;
        *reinterpret_cast<uint4*>(wb + KO + 5120 + lane*80 + 48) = z;
    }

    // ---- stage patch X (reflect-padded) as bf16 [64][40] ----
    #pragma unroll
    for (int i = 0; i < 8; ++i) {
        int v = lane + 64*i;              // 0..511 float4s
        int tok = v >> 3, qf = v & 7;
        int pr = tok >> 3, pc = tok & 7;
        int ar = wi*4 + pr; if (ar >= HH) ar = 2*(HH-1) - ar;
        int ac = wj*4 + pc; if (ac >= WW) ac = 2*(WW-1) - ac;
        float4 xv = reinterpret_cast<const float4*>(x)[ (((t_i*HH + ar)*WW) + ac)*8 + qf ];
        ushort4 o; o.x = f2bf(xv.x); o.y = f2bf(xv.y); o.z = f2bf(xv.z); o.w = f2bf(xv.w);
        *reinterpret_cast<ushort4*>(wb + XO + tok*80 + qf*8) = o;
    }

    // ---- QKV GEMM: [64x32] @ [32x96], bias in C-init; write Q,K,V to LDS layouts ----
    bf16x8 xa[4];
    #pragma unroll
    for (int mt = 0; mt < 4; ++mt)
        xa[mt] = *reinterpret_cast<const bf16x8*>(wb + XO + (ln + 16*mt)*80 + g*16);
    #pragma unroll
    for (int nt = 0; nt < 6; ++nt) {
        bf16x8 wq = *reinterpret_cast<const bf16x8*>(smem + SWO + (ln + 16*nt)*80 + g*16);
        float bias = qkv_b[nt*16 + ln];
        #pragma unroll
        for (int mt = 0; mt < 4; ++mt) {
            f32x4 acc = {bias, bias, bias, bias};
            acc = __builtin_amdgcn_mfma_f32_16x16x32_bf16(xa[mt], wq, acc, 0, 0, 0);
            #pragma unroll
            for (int r = 0; r < 4; ++r) {
                int l = mt*16 + g*4 + r;
                float val = acc[r];
                if (nt < 2) {        // Q head nt, pre-scaled
                    *reinterpret_cast<uint16_t*>(wb + QO + nt*3072 + l*48 + ln*2) = f2bf(val * 0.25f);
                } else if (nt < 4) { // K head nt-2
                    *reinterpret_cast<uint16_t*>(wb + KO + (nt-2)*5120 + l*80 + ln*2) = f2bf(val);
                } else {             // V head nt-4, stored transposed [d][m]
                    *reinterpret_cast<uint16_t*>(wb + VO + (nt-4)*2304 + ln*144 + l*2) = f2bf(val);
                }
            }
        }
    }

    // ---- per-head attention ----
    #pragma unroll
    for (int h = 0; h < 2; ++h) {
        bf16x8 qa[4], kb[4];
        #pragma unroll
        for (int mt = 0; mt < 4; ++mt)
            qa[mt] = *reinterpret_cast<const bf16x8*>(wb + QO + h*3072 + (ln + 16*mt)*48 + g*16);
        #pragma unroll
        for (int nt = 0; nt < 4; ++nt)
            kb[nt] = *reinterpret_cast<const bf16x8*>(wb + KO + h*5120 + (ln + 16*nt)*80 + g*16);

        f32x4 sc[4][4];
        #pragma unroll
        for (int mt = 0; mt < 4; ++mt) {
            #pragma unroll
            for (int nt = 0; nt < 4; ++nt) {
                const int m = nt*16 + ln;
                const int l0 = mt*16 + g*4;
                f32x4 bi;
                #pragma unroll
                for (int r = 0; r < 4; ++r) {
                    int idx = rel_idx[(l0 + r)*64 + m];
                    uint32_t pp = *reinterpret_cast<const uint32_t*>(smem + STO + idx*4);
                    bi[r] = bf2f((uint16_t)(pp >> (16*h)));
                }
                sc[mt][nt] = __builtin_amdgcn_mfma_f32_16x16x32_bf16(qa[mt], kb[nt], bi, 0, 0, 0);
            }
        }

        // softmax over m (cols spread across ln-lanes and nt)
        float rinv[4][4];
        #pragma unroll
        for (int mt = 0; mt < 4; ++mt) {
            #pragma unroll
            for (int r = 0; r < 4; ++r) {
                float mx = fmaxf(fmaxf(sc[mt][0][r], sc[mt][1][r]),
                                 fmaxf(sc[mt][2][r], sc[mt][3][r]));
                mx = fmaxf(mx, __shfl_xor(mx, 1));
                mx = fmaxf(mx, __shfl_xor(mx, 2));
                mx = fmaxf(mx, __shfl_xor(mx, 4));
                mx = fmaxf(mx, __shfl_xor(mx, 8));
                float s = 0.f;
                #pragma unroll
                for (int nt = 0; nt < 4; ++nt) {
                    float e = __expf(sc[mt][nt][r] - mx);
                    sc[mt][nt][r] = e; s += e;
                }
                s += __shfl_xor(s, 1);
                s += __shfl_xor(s, 2);
                s += __shfl_xor(s, 4);
                s += __shfl_xor(s, 8);
                rinv[mt][r] = 1.0f / s;
            }
        }

        // PV: P (bf16, via LDS half-tiles) @ V
        f32x4 oacc[4];
        #pragma unroll
        for (int mt = 0; mt < 4; ++mt) { f32x4 zz = {0.f,0.f,0.f,0.f}; oacc[mt] = zz; }
        #pragma unroll
        for (int kc = 0; kc < 2; ++kc) {
            #pragma unroll
            for (int mt = 0; mt < 4; ++mt) {
                #pragma unroll
                for (int half = 0; half < 2; ++half) {
                    int nt = kc*2 + half;
                    #pragma unroll
                    for (int r = 0; r < 4; ++r) {
                        int l = mt*16 + g*4 + r;
                        *reinterpret_cast<uint16_t*>(wb + XO + l*80 + (half*16 + ln)*2)
                            = f2bf(sc[mt][nt][r]);
                    }
                }
            }
            bf16x8 vb = *reinterpret_cast<const bf16x8*>(wb + VO + h*2304 + ln*144 + kc*64 + g*16);
            #pragma unroll
            for (int mt = 0; mt < 4; ++mt) {
                bf16x8 pa = *reinterpret_cast<const bf16x8*>(wb + XO + (ln + 16*mt)*80 + g*16);
                oacc[mt] = __builtin_amdgcn_mfma_f32_16x16x32_bf16(pa, vb, oacc[mt], 0, 0, 0);
            }
        }
        // normalize + write attn-out columns of this head
        #pragma unroll
        for (int mt = 0; mt < 4; ++mt) {
            #pragma unroll
            for (int r = 0; r < 4; ++r) {
                int l = mt*16 + g*4 + r;
                *reinterpret_cast<uint16_t*>(wb + OO + l*80 + (h*16 + ln)*2)
                    = f2bf(oacc[mt][r] * rinv[mt][r]);
            }
        }
    }

    // ---- proj: [64x32] @ [32x32] + scatter/store ----
    bf16x8 oa[4];
    #pragma unroll
    for (int mt = 0; mt < 4; ++mt)
        oa[mt] = *reinterpret_cast<const bf16x8*>(wb + OO + (ln + 16*mt)*80 + g*16);
    #pragma unroll
    for (int nt = 0; nt < 2; ++nt) {
        bf16x8 pw = *reinterpret_cast<const bf16x8*>(smem + SPO + (ln + 16*nt)*80 + g*16);
        float bias = proj_b[nt*16 + ln];
        #pragma unroll
        for (int mt = 0; mt < 4; ++mt) {
            f32x4 acc = {bias, bias, bias, bias};
            acc = __builtin_amdgcn_mfma_f32_16x16x32_bf16(oa[mt], pw, acc, 0, 0, 0);
            #pragma unroll
            for (int r = 0; r < 4; ++r) {
                int l = mt*16 + g*4 + r;
                int co = nt*16 + ln;
                float val = acc[r];
                if (WSPATH) {
                    ws[((size_t)wid*64 + l)*32 + co] = f2bf(val);
                } else {
                    int pr = l >> 3, pc = l & 7;
                    int ar = wi*4 + pr; if (ar >= HH) ar = 2*(HH-1) - ar;
                    int ac = wj*4 + pc; if (ac >= WW) ac = 2*(WW-1) - ac;
                    atomicAdd(out + (((t_i*HH + ar)*WW + ac)*32 + co), val);
                }
            }
        }
    }
}

// gather <=3x3 contributing windows per output pixel, divide by count
__global__ __launch_bounds__(256) void gather_out(const uint16_t* __restrict__ ws,
                                                  float* __restrict__ out)
{
    int gid = blockIdx.x * 256 + threadIdx.x;   // 1,048,576 = pixels * 8 float4s
    int q = gid & 7;
    int c = (gid >> 3) & 127;
    int r = (gid >> 10) & 127;
    int t = gid >> 17;

    int wr[3], pr[3], nr = 0;
    { int w0 = r >> 2;
      wr[0] = w0; pr[0] = r & 3; nr = 1;
      if (w0 >= 1) { wr[nr] = w0 - 1; pr[nr] = (r & 3) + 4; nr++; }
      if (r >= 123 && r <= 126) { wr[nr] = 31; pr[nr] = 130 - r; nr++; } }
    int wc[3], pc[3], nc = 0;
    { int w0 = c >> 2;
      wc[0] = w0; pc[0] = c & 3; nc = 1;
      if (w0 >= 1) { wc[nc] = w0 - 1; pc[nc] = (c & 3) + 4; nc++; }
      if (c >= 123 && c <= 126) { wc[nc] = 31; pc[nc] = 130 - c; nc++; } }

    float4 acc; acc.x = acc.y = acc.z = acc.w = 0.f;
    #pragma unroll
    for (int i = 0; i < 3; ++i) {
        #pragma unroll
        for (int j = 0; j < 3; ++j) {
            if (i < nr && j < nc) {
                int win = t*1024 + wr[i]*32 + wc[j];
                int tok = pr[i]*8 + pc[j];
                ushort4 v = *reinterpret_cast<const ushort4*>(ws + ((size_t)win*64 + tok)*32 + q*4);
                acc.x += bf2f(v.x); acc.y += bf2f(v.y); acc.z += bf2f(v.z); acc.w += bf2f(v.w);
            }
        }
    }
    float inv = 1.0f / ((float)(nr*nc) + 1e-10f);
    acc.x *= inv; acc.y *= inv; acc.z *= inv; acc.w *= inv;
    reinterpret_cast<float4*>(out)[gid] = acc;
}

// fallback normalize (atomic path)
__global__ __launch_bounds__(256) void div_kernel(float* __restrict__ out)
{
    int gid = blockIdx.x*blockDim.x + threadIdx.x;
    const int total4 = T_*HH*WW*32/4;
    if (gid >= total4) return;
    int pix = gid >> 3;
    int c_ = pix % WW;
    int r_ = (pix / WW) % HH;
    int cr = 0, cc = 0;
    for (int i = 0; i < 32; ++i) {
        #pragma unroll
        for (int p = 0; p < 8; ++p) {
            int rr = i*4 + p; if (rr >= HH) rr = 2*(HH-1) - rr;
            cr += (rr == r_);
            int aa = i*4 + p; if (aa >= WW) aa = 2*(WW-1) - aa;
            cc += (aa == c_);
        }
    }
    float inv = 1.f / ((float)cr*(float)cc + 1e-10f);
    float4* p4 = reinterpret_cast<float4*>(out) + gid;
    float4 v = *p4;
    v.x *= inv; v.y *= inv; v.z *= inv; v.w *= inv;
    *p4 = v;
}

extern "C" void kernel_launch(void* const* d_in, const int* in_sizes, int n_in,
                              void* d_out, int out_size, void* d_ws, size_t ws_size,
                              hipStream_t stream) {
    const float* x       = (const float*)d_in[0];
    const float* qkv_w   = (const float*)d_in[1];
    const float* qkv_b   = (const float*)d_in[2];
    const float* rel_tab = (const float*)d_in[3];
    const float* proj_w  = (const float*)d_in[4];
    const float* proj_b  = (const float*)d_in[5];
    const int*   rel_idx = (const int*)d_in[6];
    float* out = (float*)d_out;

    const size_t need = (size_t)NWIN * 64 * 32 * 2;   // 33.5 MB bf16 per-window outputs
    if (ws_size >= need) {
        win_attn<1><<<NWIN/2, 128, 0, stream>>>(x, qkv_w, qkv_b, rel_tab, proj_w, proj_b,
                                                rel_idx, (uint16_t*)d_ws, out);
        gather_out<<<4096, 256, 0, stream>>>((const uint16_t*)d_ws, out);
    } else {
        hipMemsetAsync(out, 0, (size_t)out_size*sizeof(float), stream);
        win_attn<0><<<NWIN/2, 128, 0, stream>>>(x, qkv_w, qkv_b, rel_tab, proj_w, proj_b,
                                                rel_idx, (uint16_t*)d_ws, out);
        const int tot4 = T_*HH*WW*32/4;
        div_kernel<<<(tot4 + 255)/256, 256, 0, stream>>>(out);
    }
}

// Round 3
// 87.815 us; speedup vs baseline: 15.2809x; 1.6030x over previous
//
#include <hip/hip_runtime.h>
#include <hip/hip_bf16.h>
#include <stdint.h>

#define NWIN 8192
typedef __attribute__((ext_vector_type(8))) short bf16x8;
typedef __attribute__((ext_vector_type(4))) float f32x4;

// ---- per-wave LDS map (byte offsets from wave base), all 16B-aligned ----
// Q: [2][64][48] @0 ; K: [2][64][48] @6144 ; P [64][144] overlays @0 after frags in regs
#define K_OFF   6144
#define VT_O    12288   /* [2][16][144] */
#define O_OFF   16896   /* [64][80] */
#define PW      22016
// shared per block
#define TAB_O   44032   /* 225 u32 packed (h0|h1) bias * LOG2E */
#define ZERO_O  44944   /* 16B zeros for k>=16 fragment halves */
#define SMEM    44960

#define LOG2E 1.44269504088896340736f

__device__ __forceinline__ uint16_t bf1(float a) {
    union { float f; uint32_t u; } c; c.f = a;
    uint32_t u = c.u;
    u += 0x7fffu + ((u >> 16) & 1u);
    return (uint16_t)(u >> 16);
}
__device__ __forceinline__ float bfu2f(uint32_t u16bits) {   // low 16 bits -> f32
    union { uint32_t u; float f; } c; c.u = u16bits << 16; return c.f;
}
__device__ __forceinline__ uint32_t pk2(float a, float b) {
    union { __hip_bfloat162 h; uint32_t u; } c;
    c.h = __float22bfloat162_rn(make_float2(a, b));
    return c.u;
}
__device__ __forceinline__ bf16x8 mk8(uint32_t a, uint32_t b, uint32_t c, uint32_t d) {
    union { bf16x8 v; uint32_t u[4]; } z;
    z.u[0] = a; z.u[1] = b; z.u[2] = c; z.u[3] = d;
    return z.v;
}

template<int WSPATH>
__global__ __launch_bounds__(128) void win_attn(
    const float* __restrict__ x, const float* __restrict__ qkv_w,
    const float* __restrict__ qkv_b, const float* __restrict__ rel_tab,
    const float* __restrict__ proj_w, const float* __restrict__ proj_b,
    uint16_t* __restrict__ ws, float* __restrict__ out)
{
    __shared__ __align__(16) char smem[SMEM];
    const int tid = threadIdx.x;
    const int wv = tid >> 6, lane = tid & 63;
    const int g = lane >> 4, ln = lane & 15;
    const int wid = blockIdx.x * 2 + wv;
    const int t_i = wid >> 10, wi = (wid >> 5) & 31, wj = wid & 31;
    char* wb = smem + wv * PW;

    // ---- shared staging: packed bias table (scaled by LOG2E) + zero pad ----
    for (int i = tid; i < 225; i += 128) {
        uint32_t lo = bf1(rel_tab[2*i]   * LOG2E);
        uint32_t hi = bf1(rel_tab[2*i+1] * LOG2E);
        *reinterpret_cast<uint32_t*>(smem + TAB_O + 4*i) = lo | (hi << 16);
    }
    if (tid < 4) *reinterpret_cast<uint32_t*>(smem + ZERO_O + 4*tid) = 0u;

    // ---- global loads, issued early ----
    float4 xr[4][2];
    #pragma unroll
    for (int nt = 0; nt < 4; ++nt) {
        int tok = 16*nt + ln;
        int pr = tok >> 3, pc = tok & 7;
        int ar = wi*4 + pr; if (ar >= 128) ar = 254 - ar;
        int ac = wj*4 + pc; if (ac >= 128) ac = 254 - ac;
        const float4* p = reinterpret_cast<const float4*>(x + (((t_i*128 + ar)*128) + ac)*32 + 8*g);
        xr[nt][0] = p[0]; xr[nt][1] = p[1];
    }
    float4 wr[6][2];
    #pragma unroll
    for (int mt = 0; mt < 6; ++mt) {
        const float4* p = reinterpret_cast<const float4*>(qkv_w + (ln + 16*mt)*32 + 8*g);
        wr[mt][0] = p[0]; wr[mt][1] = p[1];
    }
    float4 qb4[6];
    #pragma unroll
    for (int mt = 0; mt < 6; ++mt)
        qb4[mt] = *reinterpret_cast<const float4*>(qkv_b + 16*mt + 4*g);

    __syncthreads();   // the only barrier: table + zero pad ready

    // ---- convert fragments ----
    bf16x8 xf[4], wf[6];
    #pragma unroll
    for (int nt = 0; nt < 4; ++nt)
        xf[nt] = mk8(pk2(xr[nt][0].x, xr[nt][0].y), pk2(xr[nt][0].z, xr[nt][0].w),
                     pk2(xr[nt][1].x, xr[nt][1].y), pk2(xr[nt][1].z, xr[nt][1].w));
    #pragma unroll
    for (int mt = 0; mt < 6; ++mt)
        wf[mt] = mk8(pk2(wr[mt][0].x, wr[mt][0].y), pk2(wr[mt][0].z, wr[mt][0].w),
                     pk2(wr[mt][1].x, wr[mt][1].y), pk2(wr[mt][1].z, wr[mt][1].w));

    const float QS = 0.25f * LOG2E;   // head_dim^-0.5 folded with log2e (exp2 softmax)

    // ---- QKV (swapped): D[wrow][tok] = W X^T + b ; packed stores of Q/K ----
    #pragma unroll
    for (int mt = 0; mt < 6; ++mt) {
        #pragma unroll
        for (int nt = 0; nt < 4; ++nt) {
            f32x4 acc;
            acc[0] = qb4[mt].x; acc[1] = qb4[mt].y; acc[2] = qb4[mt].z; acc[3] = qb4[mt].w;
            acc = __builtin_amdgcn_mfma_f32_16x16x32_bf16(wf[mt], xf[nt], acc, 0, 0, 0);
            const int l = 16*nt + ln;          // token (column)
            if (mt < 2) {                      // Q head mt, pre-scaled; d = 4g..4g+3
                uint2 u;
                u.x = pk2(acc[0]*QS, acc[1]*QS);
                u.y = pk2(acc[2]*QS, acc[3]*QS);
                *reinterpret_cast<uint2*>(wb + mt*3072 + l*48 + 8*g) = u;
            } else if (mt < 4) {               // K head mt-2
                uint2 u;
                u.x = pk2(acc[0], acc[1]);
                u.y = pk2(acc[2], acc[3]);
                *reinterpret_cast<uint2*>(wb + K_OFF + (mt-2)*3072 + l*48 + 8*g) = u;
            } else {                           // V head mt-4, stored [d][m]
                #pragma unroll
                for (int r = 0; r < 4; ++r)
                    *reinterpret_cast<uint16_t*>(wb + VT_O + (mt-4)*2304 + (4*g + r)*144 + l*2)
                        = bf1(acc[r]);
            }
        }
    }

    // ---- load ALL Q/K fragments (both heads) into regs before P overlays the region ----
    bf16x8 qa[2][4], kb[2][4];
    #pragma unroll
    for (int h = 0; h < 2; ++h) {
        #pragma unroll
        for (int i = 0; i < 4; ++i) {
            const char* kp = (g < 2) ? (wb + K_OFF + h*3072 + (ln + 16*i)*48 + 16*g)
                                     : (smem + ZERO_O);
            kb[h][i] = *reinterpret_cast<const bf16x8*>(kp);
            const char* qp = (g < 2) ? (wb + h*3072 + (ln + 16*i)*48 + 16*g)
                                     : (smem + ZERO_O);
            qa[h][i] = *reinterpret_cast<const bf16x8*>(qp);
        }
    }

    // proj weights/bias direct from global (hidden under attention)
    float4 w2r[2][2];
    #pragma unroll
    for (int nt = 0; nt < 2; ++nt) {
        const float4* p = reinterpret_cast<const float4*>(proj_w + (ln + 16*nt)*32 + 8*g);
        w2r[nt][0] = p[0]; w2r[nt][1] = p[1];
    }
    float pb[2];
    pb[0] = proj_b[ln]; pb[1] = proj_b[16 + ln];

    // ---- per-head attention ----
    #pragma unroll
    for (int h = 0; h < 2; ++h) {
        // S^T = mfma(K, Q): rows m = 16mt+4g+r, cols l = 16nt+ln ; bias as C-init
        f32x4 sc[4][4];
        #pragma unroll
        for (int mt = 0; mt < 4; ++mt) {
            #pragma unroll
            for (int nt = 0; nt < 4; ++nt) {
                const int dr  = 2*nt + (ln >> 3) - 2*mt - (g >> 1) + 7;   // (l>>3)-(m>>3)+7
                const int dc3 = (ln & 7) - 4*(g & 1) + 4;                 // dc at r=3
                const char* tb = smem + TAB_O + 4*(dr*15 + dc3);
                uint32_t b3 = *reinterpret_cast<const uint32_t*>(tb);
                uint32_t b2 = *reinterpret_cast<const uint32_t*>(tb + 4);
                uint32_t b1 = *reinterpret_cast<const uint32_t*>(tb + 8);
                uint32_t b0 = *reinterpret_cast<const uint32_t*>(tb + 12);
                f32x4 bi;
                if (h == 0) {
                    bi[0] = bfu2f(b0 & 0xffffu); bi[1] = bfu2f(b1 & 0xffffu);
                    bi[2] = bfu2f(b2 & 0xffffu); bi[3] = bfu2f(b3 & 0xffffu);
                } else {
                    bi[0] = bfu2f(b0 >> 16); bi[1] = bfu2f(b1 >> 16);
                    bi[2] = bfu2f(b2 >> 16); bi[3] = bfu2f(b3 >> 16);
                }
                sc[mt][nt] = __builtin_amdgcn_mfma_f32_16x16x32_bf16(kb[h][mt], qa[h][nt], bi, 0, 0, 0);
            }
        }

        // softmax over m: 16 in-lane values (mt,r) + cross-g (shfl 16,32); exp2 domain
        float rinv[4];
        #pragma unroll
        for (int nt = 0; nt < 4; ++nt) {
            float mx = sc[0][nt][0];
            #pragma unroll
            for (int mt = 0; mt < 4; ++mt)
                #pragma unroll
                for (int r = 0; r < 4; ++r) mx = fmaxf(mx, sc[mt][nt][r]);
            mx = fmaxf(mx, __shfl_xor(mx, 16));
            mx = fmaxf(mx, __shfl_xor(mx, 32));
            float sum = 0.f;
            #pragma unroll
            for (int mt = 0; mt < 4; ++mt) {
                #pragma unroll
                for (int r = 0; r < 4; ++r) {
                    float e = exp2f(sc[mt][nt][r] - mx);
                    sc[mt][nt][r] = e; sum += e;
                }
            }
            sum += __shfl_xor(sum, 16);
            sum += __shfl_xor(sum, 32);
            rinv[nt] = 1.0f / sum;
        }

        // P store (normalized, packed b64): P[l][m], contiguous in m
        #pragma unroll
        for (int nt = 0; nt < 4; ++nt) {
            #pragma unroll
            for (int mt = 0; mt < 4; ++mt) {
                uint2 u;
                u.x = pk2(sc[mt][nt][0]*rinv[nt], sc[mt][nt][1]*rinv[nt]);
                u.y = pk2(sc[mt][nt][2]*rinv[nt], sc[mt][nt][3]*rinv[nt]);
                *reinterpret_cast<uint2*>(wb + (16*nt + ln)*144 + (16*mt + 4*g)*2) = u;
            }
        }

        // PV: A = P[l][m], B = VT[d][m]  -> O rows l, cols d
        bf16x8 vb0 = *reinterpret_cast<const bf16x8*>(wb + VT_O + h*2304 + ln*144 + 16*g);
        bf16x8 vb1 = *reinterpret_cast<const bf16x8*>(wb + VT_O + h*2304 + ln*144 + 16*g + 64);
        f32x4 oacc[4];
        #pragma unroll
        for (int mt = 0; mt < 4; ++mt) { f32x4 z = {0.f,0.f,0.f,0.f}; oacc[mt] = z; }
        #pragma unroll
        for (int mt = 0; mt < 4; ++mt) {
            bf16x8 pa0 = *reinterpret_cast<const bf16x8*>(wb + (ln + 16*mt)*144 + 16*g);
            bf16x8 pa1 = *reinterpret_cast<const bf16x8*>(wb + (ln + 16*mt)*144 + 16*g + 64);
            oacc[mt] = __builtin_amdgcn_mfma_f32_16x16x32_bf16(pa0, vb0, oacc[mt], 0, 0, 0);
            oacc[mt] = __builtin_amdgcn_mfma_f32_16x16x32_bf16(pa1, vb1, oacc[mt], 0, 0, 0);
        }
        // O store: rows l = 16mt+4g+r, col 16h+ln
        #pragma unroll
        for (int mt = 0; mt < 4; ++mt)
            #pragma unroll
            for (int r = 0; r < 4; ++r)
                *reinterpret_cast<uint16_t*>(wb + O_OFF + (16*mt + 4*g + r)*80 + (16*h + ln)*2)
                    = bf1(oacc[mt][r]);
    }

    // ---- proj: A = O[l][c], B = W2[co][c] ; output rows l, cols co ----
    bf16x8 w2f[2];
    #pragma unroll
    for (int nt = 0; nt < 2; ++nt)
        w2f[nt] = mk8(pk2(w2r[nt][0].x, w2r[nt][0].y), pk2(w2r[nt][0].z, w2r[nt][0].w),
                      pk2(w2r[nt][1].x, w2r[nt][1].y), pk2(w2r[nt][1].z, w2r[nt][1].w));
    bf16x8 oa[4];
    #pragma unroll
    for (int mt = 0; mt < 4; ++mt)
        oa[mt] = *reinterpret_cast<const bf16x8*>(wb + O_OFF + (ln + 16*mt)*80 + 16*g);
    #pragma unroll
    for (int nt = 0; nt < 2; ++nt) {
        #pragma unroll
        for (int mt = 0; mt < 4; ++mt) {
            f32x4 acc = {pb[nt], pb[nt], pb[nt], pb[nt]};
            acc = __builtin_amdgcn_mfma_f32_16x16x32_bf16(oa[mt], w2f[nt], acc, 0, 0, 0);
            #pragma unroll
            for (int r = 0; r < 4; ++r) {
                const int l = 16*mt + 4*g + r;
                const int co = 16*nt + ln;
                if (WSPATH) {
                    ws[((size_t)wid*64 + l)*32 + co] = bf1(acc[r]);
                } else {
                    int pr = l >> 3, pc = l & 7;
                    int ar = wi*4 + pr; if (ar >= 128) ar = 254 - ar;
                    int ac = wj*4 + pc; if (ac >= 128) ac = 254 - ac;
                    atomicAdd(out + (((t_i*128 + ar)*128 + ac)*32 + co), acc[r]);
                }
            }
        }
    }
}

// gather <=3x3 contributing windows per output pixel, divide by count
__global__ __launch_bounds__(256) void gather_out(const uint16_t* __restrict__ ws,
                                                  float* __restrict__ out)
{
    int gid = blockIdx.x * 256 + threadIdx.x;   // pixels * 8 float4s
    int q = gid & 7;
    int c = (gid >> 3) & 127;
    int r = (gid >> 10) & 127;
    int t = gid >> 17;

    int wr[3], pr[3], nr = 0;
    { int w0 = r >> 2;
      wr[0] = w0; pr[0] = r & 3; nr = 1;
      if (w0 >= 1) { wr[nr] = w0 - 1; pr[nr] = (r & 3) + 4; nr++; }
      if (r >= 123 && r <= 126) { wr[nr] = 31; pr[nr] = 130 - r; nr++; } }
    int wc[3], pc[3], nc = 0;
    { int w0 = c >> 2;
      wc[0] = w0; pc[0] = c & 3; nc = 1;
      if (w0 >= 1) { wc[nc] = w0 - 1; pc[nc] = (c & 3) + 4; nc++; }
      if (c >= 123 && c <= 126) { wc[nc] = 31; pc[nc] = 130 - c; nc++; } }

    float4 acc; acc.x = acc.y = acc.z = acc.w = 0.f;
    #pragma unroll
    for (int i = 0; i < 3; ++i) {
        #pragma unroll
        for (int j = 0; j < 3; ++j) {
            if (i < nr && j < nc) {
                int win = t*1024 + wr[i]*32 + wc[j];
                int tok = pr[i]*8 + pc[j];
                ushort4 v = *reinterpret_cast<const ushort4*>(ws + ((size_t)win*64 + tok)*32 + q*4);
                union { uint32_t u; float f; } a0,a1,a2,a3;
                a0.u = (uint32_t)v.x << 16; a1.u = (uint32_t)v.y << 16;
                a2.u = (uint32_t)v.z << 16; a3.u = (uint32_t)v.w << 16;
                acc.x += a0.f; acc.y += a1.f; acc.z += a2.f; acc.w += a3.f;
            }
        }
    }
    float inv = 1.0f / ((float)(nr*nc) + 1e-10f);
    acc.x *= inv; acc.y *= inv; acc.z *= inv; acc.w *= inv;
    reinterpret_cast<float4*>(out)[gid] = acc;
}

// fallback normalize (atomic path)
__global__ __launch_bounds__(256) void div_kernel(float* __restrict__ out)
{
    int gid = blockIdx.x*blockDim.x + threadIdx.x;
    const int total4 = 8*128*128*32/4;
    if (gid >= total4) return;
    int pix = gid >> 3;
    int c_ = pix % 128;
    int r_ = (pix / 128) % 128;
    int cr = 0, cc = 0;
    for (int i = 0; i < 32; ++i) {
        #pragma unroll
        for (int p = 0; p < 8; ++p) {
            int rr = i*4 + p; if (rr >= 128) rr = 254 - rr;
            cr += (rr == r_);
            int aa = i*4 + p; if (aa >= 128) aa = 254 - aa;
            cc += (aa == c_);
        }
    }
    float inv = 1.f / ((float)cr*(float)cc + 1e-10f);
    float4* p4 = reinterpret_cast<float4*>(out) + gid;
    float4 v = *p4;
    v.x *= inv; v.y *= inv; v.z *= inv; v.w *= inv;
    *p4 = v;
}

extern "C" void kernel_launch(void* const* d_in, const int* in_sizes, int n_in,
                              void* d_out, int out_size, void* d_ws, size_t ws_size,
                              hipStream_t stream) {
    const float* x       = (const float*)d_in[0];
    const float* qkv_w   = (const float*)d_in[1];
    const float* qkv_b   = (const float*)d_in[2];
    const float* rel_tab = (const float*)d_in[3];
    const float* proj_w  = (const float*)d_in[4];
    const float* proj_b  = (const float*)d_in[5];
    float* out = (float*)d_out;

    const size_t need = (size_t)NWIN * 64 * 32 * 2;   // 33.5 MB bf16 per-window outputs
    if (ws_size >= need) {
        win_attn<1><<<NWIN/2, 128, 0, stream>>>(x, qkv_w, qkv_b, rel_tab, proj_w, proj_b,
                                                (uint16_t*)d_ws, out);
        gather_out<<<4096, 256, 0, stream>>>((const uint16_t*)d_ws, out);
    } else {
        hipMemsetAsync(out, 0, (size_t)out_size*sizeof(float), stream);
        win_attn<0><<<NWIN/2, 128, 0, stream>>>(x, qkv_w, qkv_b, rel_tab, proj_w, proj_b,
                                                (uint16_t*)d_ws, out);
        const int tot4 = 8*128*128*32/4;
        div_kernel<<<(tot4 + 255)/256, 256, 0, stream>>>(out);
    }
}

// Round 4
// 69.241 us; speedup vs baseline: 19.3800x; 1.2682x over previous
//
#include <hip/hip_runtime.h>
#include <hip/hip_bf16.h>
#include <stdint.h>

#define NWIN 8192
typedef __attribute__((ext_vector_type(8))) short bf16x8;
typedef __attribute__((ext_vector_type(4))) float f32x4;

#define LOG2E 1.44269504088896340736f
#define QSCALE (0.25f * LOG2E)

// ---- workspace layout (bytes) ----
#define WS_BIASC 0        /* 32768: f32 bias in C-frag layout [h][mt][nt][lane][4] */
#define WS_QKVW  32768    /* 6144: bf16 [96][32], Q rows prescaled by QSCALE */
#define WS_PROJW 38912    /* 2048: bf16 [32][32] */
#define WS_QKVB  40960    /* 384: f32 [96], Q rows prescaled */
#define WS_OUT   41472    /* bf16 [8192][64][32] per-window outputs */
#define WS_NEED  (WS_OUT + (size_t)NWIN*64*32*2)

// ---- LDS layout (16384 B per 1-wave block) ----
// QK @0: Q0@0 Q1@2048 K0@4096 K1@6144 — [64 tok][16 d] stride 32B, swz ^((tok&4)<<2)
// (P [64][64] stride 128B, swz ^((l&7)<<4), overlays QK after frags are in regs)
#define V_O  8192   /* [2 h][64 m][16 d] linear stride 32B */
#define OT_O 12288  /* O^T subtiled: block(lb=mt, cb=c/4) @ (mt*8+cb)*128, [4 c][16 l]; first 16B = zero pad */

__device__ __forceinline__ uint16_t bf1(float a){
    union{float f;uint32_t u;}c; c.f=a; uint32_t u=c.u;
    u += 0x7fffu + ((u>>16)&1u); return (uint16_t)(u>>16);
}
__device__ __forceinline__ uint32_t pk2(float a,float b){
    union{__hip_bfloat162 h;uint32_t u;}c;
    c.h=__float22bfloat162_rn(make_float2(a,b)); return c.u;
}
template<int OFF>
__device__ __forceinline__ uint2 tr16(uint32_t a){
    uint2 d;
    asm volatile("ds_read_b64_tr_b16 %0, %1 offset:%2" : "=v"(d) : "v"(a), "i"(OFF) : "memory");
    return d;
}
__device__ __forceinline__ void lgkm0(){
    asm volatile("s_waitcnt lgkmcnt(0)" ::: "memory");
    __builtin_amdgcn_sched_barrier(0);
}
__device__ __forceinline__ bf16x8 mk8u(uint2 a, uint2 b){
    union{bf16x8 v;uint32_t u[4];}z; z.u[0]=a.x; z.u[1]=a.y; z.u[2]=b.x; z.u[3]=b.y; return z.v;
}
__device__ __forceinline__ float m4(f32x4 v){ return fmaxf(fmaxf(v[0],v[1]),fmaxf(v[2],v[3])); }
__device__ __forceinline__ float s4(f32x4 v){ return (v[0]+v[1])+(v[2]+v[3]); }

// one-time: bf16 weights (Q prescaled), prescaled bias, rel-pos bias in MFMA C-layout
__global__ __launch_bounds__(256) void prep(const float* __restrict__ qkv_w,
                                            const float* __restrict__ qkv_b,
                                            const float* __restrict__ rel_tab,
                                            const float* __restrict__ proj_w,
                                            char* __restrict__ ws)
{
    int t = blockIdx.x*256 + threadIdx.x;   // 0..4095
    if (t < 2048) {                          // biasC: [h][mt][nt][lane][4] f32
        int lanei = t & 63, tile = t >> 6;
        int h = tile >> 4, mt = (tile >> 2) & 3, nt = tile & 3;
        int gg = lanei >> 4, lnn = lanei & 15;
        int l = 16*nt + lnn;
        float* biasC = (float*)(ws + WS_BIASC);
        #pragma unroll
        for (int r = 0; r < 4; ++r) {
            int m = 16*mt + 4*gg + r;
            int dr = (l >> 3) - (m >> 3) + 7;
            int dc = (l & 7) - (m & 7) + 7;
            biasC[t*4 + r] = rel_tab[(dr*15 + dc)*2 + h] * LOG2E;
        }
    } else if (t < 3584) {                   // qkv_w -> bf16, Q rows scaled
        int e = (t - 2048) * 2;
        int row = e >> 5;
        float s = (row < 32) ? QSCALE : 1.0f;
        *(uint32_t*)(ws + WS_QKVW + e*2) = pk2(qkv_w[e]*s, qkv_w[e+1]*s);
    } else {                                 // proj_w -> bf16
        int e = (t - 3584) * 2;
        *(uint32_t*)(ws + WS_PROJW + e*2) = pk2(proj_w[e], proj_w[e+1]);
    }
    if (t < 96) {
        float s = (t < 32) ? QSCALE : 1.0f;
        ((float*)(ws + WS_QKVB))[t] = qkv_b[t] * s;
    }
}

template<int H>
__device__ __forceinline__ void head_tail(f32x4 (&sc)[4][4], f32x4 (&oacc)[4],
                                          char* smem, uint32_t L, int g, int ln)
{
    // ---- softmax over m (16 in-lane + cross-g shuffles), exp2 domain ----
    float rinv[4];
    #pragma unroll
    for (int nt = 0; nt < 4; ++nt) {
        float mx = fmaxf(fmaxf(m4(sc[0][nt]), m4(sc[1][nt])),
                         fmaxf(m4(sc[2][nt]), m4(sc[3][nt])));
        mx = fmaxf(mx, __shfl_xor(mx, 16));
        mx = fmaxf(mx, __shfl_xor(mx, 32));
        #pragma unroll
        for (int mt = 0; mt < 4; ++mt) {
            f32x4 e;
            e[0]=exp2f(sc[mt][nt][0]-mx); e[1]=exp2f(sc[mt][nt][1]-mx);
            e[2]=exp2f(sc[mt][nt][2]-mx); e[3]=exp2f(sc[mt][nt][3]-mx);
            sc[mt][nt]=e;
        }
        float sum = (s4(sc[0][nt]) + s4(sc[1][nt])) + (s4(sc[2][nt]) + s4(sc[3][nt]));
        sum += __shfl_xor(sum, 16);
        sum += __shfl_xor(sum, 32);
        rinv[nt] = 1.0f / sum;
    }
    // ---- P store: [64 l][64 m] stride 128, swz ^((l&7)<<4); packed uint2 ----
    #pragma unroll
    for (int nt = 0; nt < 4; ++nt) {
        int l = 16*nt + ln;
        #pragma unroll
        for (int mt = 0; mt < 4; ++mt) {
            uint2 u;
            u.x = pk2(sc[mt][nt][0]*rinv[nt], sc[mt][nt][1]*rinv[nt]);
            u.y = pk2(sc[mt][nt][2]*rinv[nt], sc[mt][nt][3]*rinv[nt]);
            uint32_t off = (uint32_t)((l*128 + 32*mt + 8*g) ^ ((ln & 7) << 4));
            *reinterpret_cast<uint2*>(smem + off) = u;
        }
    }
    // ---- V B-frags via hw transpose read (V linear [64 m][16 d]) ----
    uint32_t va = L + V_O + H*2048 + 256*g + 8*ln;
    uint2 v00 = tr16<0>(va),    v01 = tr16<128>(va);
    uint2 v10 = tr16<1024>(va), v11 = tr16<1152>(va);
    lgkm0();
    bf16x8 vb0 = mk8u(v00, v01), vb1 = mk8u(v10, v11);
    // ---- PV ----
    #pragma unroll
    for (int mt = 0; mt < 4; ++mt) { f32x4 z={0.f,0.f,0.f,0.f}; oacc[mt]=z; }
    #pragma unroll
    for (int mt = 0; mt < 4; ++mt) {
        uint32_t p0 = (uint32_t)(((ln+16*mt)*128 + 16*g) ^ ((ln & 7) << 4));
        uint32_t p1 = (uint32_t)(((ln+16*mt)*128 + 64 + 16*g) ^ ((ln & 7) << 4));
        bf16x8 pa0 = *reinterpret_cast<const bf16x8*>(smem + p0);
        bf16x8 pa1 = *reinterpret_cast<const bf16x8*>(smem + p1);
        oacc[mt] = __builtin_amdgcn_mfma_f32_16x16x32_bf16(pa0, vb0, oacc[mt], 0, 0, 0);
        oacc[mt] = __builtin_amdgcn_mfma_f32_16x16x32_bf16(pa1, vb1, oacc[mt], 0, 0, 0);
    }
    // ---- O^T store: block(mt, cb=4H+(ln>>2)), [4 c][16 l]; packed uint2 ----
    #pragma unroll
    for (int mt = 0; mt < 4; ++mt) {
        uint2 u; u.x = pk2(oacc[mt][0], oacc[mt][1]); u.y = pk2(oacc[mt][2], oacc[mt][3]);
        uint32_t off = (uint32_t)(OT_O + (mt*8 + 4*H + (ln>>2))*128 + (ln&3)*32 + 8*g);
        *reinterpret_cast<uint2*>(smem + off) = u;
    }
}

template<int WSPATH>
__global__ __launch_bounds__(64, 3) void win_attn(
    const float* __restrict__ x, const float* __restrict__ proj_b,
    const char* __restrict__ wsc, uint16_t* __restrict__ wout,
    float* __restrict__ out)
{
    __shared__ __align__(16) char smem[16384];
    const int lane = threadIdx.x;
    const int g = lane >> 4, ln = lane & 15;
    const int wid = blockIdx.x;
    const int t_i = wid >> 10, wi = (wid >> 5) & 31, wj = wid & 31;
    const uint32_t L = (uint32_t)(uintptr_t)(&smem[0]);

    // zero pad for Q/K g>=2 fragment halves (O^T region unused until head loop)
    if (lane < 4) *reinterpret_cast<uint32_t*>(smem + OT_O + 4*lane) = 0u;

    const float* biasC = (const float*)(wsc + WS_BIASC);
    const uint16_t* wbf  = (const uint16_t*)(wsc + WS_QKVW);
    const uint16_t* pwbf = (const uint16_t*)(wsc + WS_PROJW);
    const float* qbs = (const float*)(wsc + WS_QKVB);

    // ---- global loads ----
    float4 xr[4][2];
    #pragma unroll
    for (int nt = 0; nt < 4; ++nt) {
        int tok = 16*nt + ln;
        int pr = tok >> 3, pc = tok & 7;
        int ar = wi*4 + pr; if (ar >= 128) ar = 254 - ar;
        int ac = wj*4 + pc; if (ac >= 128) ac = 254 - ac;
        const float4* p = reinterpret_cast<const float4*>(x + (((t_i*128 + ar)*128) + ac)*32 + 8*g);
        xr[nt][0] = p[0]; xr[nt][1] = p[1];
    }
    bf16x8 wf[6];
    #pragma unroll
    for (int mt = 0; mt < 6; ++mt)
        wf[mt] = *reinterpret_cast<const bf16x8*>(wbf + (ln + 16*mt)*32 + 8*g);
    float4 qb4[6];
    #pragma unroll
    for (int mt = 0; mt < 6; ++mt)
        qb4[mt] = *reinterpret_cast<const float4*>(qbs + 16*mt + 4*g);

    bf16x8 xf[4];
    #pragma unroll
    for (int nt = 0; nt < 4; ++nt) {
        union{bf16x8 v;uint32_t u[4];} z;
        z.u[0]=pk2(xr[nt][0].x,xr[nt][0].y); z.u[1]=pk2(xr[nt][0].z,xr[nt][0].w);
        z.u[2]=pk2(xr[nt][1].x,xr[nt][1].y); z.u[3]=pk2(xr[nt][1].z,xr[nt][1].w);
        xf[nt]=z.v;
    }

    // ---- QKV GEMM (swapped): D[wrow][tok]; all stores packed uint2 ----
    #pragma unroll
    for (int mt = 0; mt < 6; ++mt) {
        #pragma unroll
        for (int nt = 0; nt < 4; ++nt) {
            f32x4 acc; acc[0]=qb4[mt].x; acc[1]=qb4[mt].y; acc[2]=qb4[mt].z; acc[3]=qb4[mt].w;
            acc = __builtin_amdgcn_mfma_f32_16x16x32_bf16(wf[mt], xf[nt], acc, 0, 0, 0);
            int tok = 16*nt + ln;
            uint2 u; u.x = pk2(acc[0],acc[1]); u.y = pk2(acc[2],acc[3]);
            uint32_t off;
            if (mt < 4) off = (uint32_t)((mt*2048 + tok*32 + 8*g) ^ ((tok & 4) << 2));
            else        off = (uint32_t)(V_O + (mt-4)*2048 + tok*32 + 8*g);
            *reinterpret_cast<uint2*>(smem + off) = u;
        }
    }

    // ---- Q/K fragments head0 (b128, swizzled; g>=2 -> zero pad) ----
    bf16x8 qa0[4], kb0[4];
    #pragma unroll
    for (int i = 0; i < 4; ++i) {
        uint32_t qoff = (g < 2) ? (uint32_t)((        (16*i+ln)*32 + 16*g) ^ ((ln & 4) << 2)) : (uint32_t)OT_O;
        uint32_t koff = (g < 2) ? (uint32_t)((4096 + (16*i+ln)*32 + 16*g) ^ ((ln & 4) << 2)) : (uint32_t)OT_O;
        qa0[i] = *reinterpret_cast<const bf16x8*>(smem + qoff);
        kb0[i] = *reinterpret_cast<const bf16x8*>(smem + koff);
    }

    // ---- head 0: S^T = mfma(K, Q) with bias C-init from precomputed table ----
    f32x4 sc[4][4];
    #pragma unroll
    for (int mt = 0; mt < 4; ++mt) {
        #pragma unroll
        for (int nt = 0; nt < 4; ++nt) {
            f32x4 bi = *reinterpret_cast<const f32x4*>(biasC + (size_t)((mt*4 + nt)*64 + lane)*4);
            sc[mt][nt] = __builtin_amdgcn_mfma_f32_16x16x32_bf16(kb0[mt], qa0[nt], bi, 0, 0, 0);
        }
    }
    // head1 Q/K frags BEFORE P overlays the QK region
    bf16x8 qa1[4], kb1[4];
    #pragma unroll
    for (int i = 0; i < 4; ++i) {
        uint32_t qoff = (g < 2) ? (uint32_t)((2048 + (16*i+ln)*32 + 16*g) ^ ((ln & 4) << 2)) : (uint32_t)OT_O;
        uint32_t koff = (g < 2) ? (uint32_t)((6144 + (16*i+ln)*32 + 16*g) ^ ((ln & 4) << 2)) : (uint32_t)OT_O;
        qa1[i] = *reinterpret_cast<const bf16x8*>(smem + qoff);
        kb1[i] = *reinterpret_cast<const bf16x8*>(smem + koff);
    }

    f32x4 oacc[4];
    head_tail<0>(sc, oacc, smem, L, g, ln);

    // ---- head 1 ----
    #pragma unroll
    for (int mt = 0; mt < 4; ++mt) {
        #pragma unroll
        for (int nt = 0; nt < 4; ++nt) {
            f32x4 bi = *reinterpret_cast<const f32x4*>(biasC + (size_t)(((16 + mt*4 + nt))*64 + lane)*4);
            sc[mt][nt] = __builtin_amdgcn_mfma_f32_16x16x32_bf16(kb1[mt], qa1[nt], bi, 0, 0, 0);
        }
    }
    head_tail<1>(sc, oacc, smem, L, g, ln);

    // ---- proj: A = O via tr-reads from O^T blocks, B = W2 (bf16 global) ----
    bf16x8 w2f[2];
    w2f[0] = *reinterpret_cast<const bf16x8*>(pwbf + ln*32 + 8*g);
    w2f[1] = *reinterpret_cast<const bf16x8*>(pwbf + (16+ln)*32 + 8*g);
    float pb2[2] = { proj_b[ln], proj_b[16+ln] };

    uint32_t ob = L + OT_O + 256*g + 8*ln;
    uint2 a0=tr16<0>(ob),    a1=tr16<128>(ob);
    uint2 b0=tr16<1024>(ob), b1=tr16<1152>(ob);
    uint2 c0=tr16<2048>(ob), c1=tr16<2176>(ob);
    uint2 d0=tr16<3072>(ob), d1=tr16<3200>(ob);
    lgkm0();
    bf16x8 oa[4];
    oa[0]=mk8u(a0,a1); oa[1]=mk8u(b0,b1); oa[2]=mk8u(c0,c1); oa[3]=mk8u(d0,d1);

    #pragma unroll
    for (int nt = 0; nt < 2; ++nt) {
        #pragma unroll
        for (int mt = 0; mt < 4; ++mt) {
            f32x4 acc = {pb2[nt], pb2[nt], pb2[nt], pb2[nt]};
            acc = __builtin_amdgcn_mfma_f32_16x16x32_bf16(oa[mt], w2f[nt], acc, 0, 0, 0);
            #pragma unroll
            for (int r = 0; r < 4; ++r) {
                int l = 16*mt + 4*g + r;
                int co = 16*nt + ln;
                if (WSPATH) {
                    wout[((size_t)wid*64 + l)*32 + co] = bf1(acc[r]);
                } else {
                    int pr = l >> 3, pc = l & 7;
                    int ar = wi*4 + pr; if (ar >= 128) ar = 254 - ar;
                    int ac = wj*4 + pc; if (ac >= 128) ac = 254 - ac;
                    atomicAdd(out + (((t_i*128 + ar)*128 + ac)*32 + co), acc[r]);
                }
            }
        }
    }
}

// gather <=3x3 contributing windows per output pixel, divide by count
__global__ __launch_bounds__(256) void gather_out(const uint16_t* __restrict__ ws,
                                                  float* __restrict__ out)
{
    int gid = blockIdx.x * 256 + threadIdx.x;   // pixels * 8 float4s
    int q = gid & 7;
    int c = (gid >> 3) & 127;
    int r = (gid >> 10) & 127;
    int t = gid >> 17;

    int wr[3], pr[3], nr = 0;
    { int w0 = r >> 2;
      wr[0] = w0; pr[0] = r & 3; nr = 1;
      if (w0 >= 1) { wr[nr] = w0 - 1; pr[nr] = (r & 3) + 4; nr++; }
      if (r >= 123 && r <= 126) { wr[nr] = 31; pr[nr] = 130 - r; nr++; } }
    int wc[3], pc[3], nc = 0;
    { int w0 = c >> 2;
      wc[0] = w0; pc[0] = c & 3; nc = 1;
      if (w0 >= 1) { wc[nc] = w0 - 1; pc[nc] = (c & 3) + 4; nc++; }
      if (c >= 123 && c <= 126) { wc[nc] = 31; pc[nc] = 130 - c; nc++; } }

    float4 acc; acc.x = acc.y = acc.z = acc.w = 0.f;
    #pragma unroll
    for (int i = 0; i < 3; ++i) {
        #pragma unroll
        for (int j = 0; j < 3; ++j) {
            if (i < nr && j < nc) {
                int win = t*1024 + wr[i]*32 + wc[j];
                int tok = pr[i]*8 + pc[j];
                ushort4 v = *reinterpret_cast<const ushort4*>(ws + ((size_t)win*64 + tok)*32 + q*4);
                union { uint32_t u; float f; } a0,a1,a2,a3;
                a0.u = (uint32_t)v.x << 16; a1.u = (uint32_t)v.y << 16;
                a2.u = (uint32_t)v.z << 16; a3.u = (uint32_t)v.w << 16;
                acc.x += a0.f; acc.y += a1.f; acc.z += a2.f; acc.w += a3.f;
            }
        }
    }
    float inv = 1.0f / ((float)(nr*nc) + 1e-10f);
    acc.x *= inv; acc.y *= inv; acc.z *= inv; acc.w *= inv;
    reinterpret_cast<float4*>(out)[gid] = acc;
}

// fallback normalize (atomic path)
__global__ __launch_bounds__(256) void div_kernel(float* __restrict__ out)
{
    int gid = blockIdx.x*blockDim.x + threadIdx.x;
    const int total4 = 8*128*128*32/4;
    if (gid >= total4) return;
    int pix = gid >> 3;
    int c_ = pix % 128;
    int r_ = (pix / 128) % 128;
    int cr = 0, cc = 0;
    for (int i = 0; i < 32; ++i) {
        #pragma unroll
        for (int p = 0; p < 8; ++p) {
            int rr = i*4 + p; if (rr >= 128) rr = 254 - rr;
            cr += (rr == r_);
            int aa = i*4 + p; if (aa >= 128) aa = 254 - aa;
            cc += (aa == c_);
        }
    }
    float inv = 1.f / ((float)cr*(float)cc + 1e-10f);
    float4* p4 = reinterpret_cast<float4*>(out) + gid;
    float4 v = *p4;
    v.x *= inv; v.y *= inv; v.z *= inv; v.w *= inv;
    *p4 = v;
}

extern "C" void kernel_launch(void* const* d_in, const int* in_sizes, int n_in,
                              void* d_out, int out_size, void* d_ws, size_t ws_size,
                              hipStream_t stream) {
    const float* x       = (const float*)d_in[0];
    const float* qkv_w   = (const float*)d_in[1];
    const float* qkv_b   = (const float*)d_in[2];
    const float* rel_tab = (const float*)d_in[3];
    const float* proj_w  = (const float*)d_in[4];
    const float* proj_b  = (const float*)d_in[5];
    float* out = (float*)d_out;
    char* ws = (char*)d_ws;

    prep<<<16, 256, 0, stream>>>(qkv_w, qkv_b, rel_tab, proj_w, ws);

    if (ws_size >= WS_NEED) {
        win_attn<1><<<NWIN, 64, 0, stream>>>(x, proj_b, (const char*)ws,
                                             (uint16_t*)(ws + WS_OUT), out);
        gather_out<<<4096, 256, 0, stream>>>((const uint16_t*)(ws + WS_OUT), out);
    } else {
        hipMemsetAsync(out, 0, (size_t)out_size*sizeof(float), stream);
        win_attn<0><<<NWIN, 64, 0, stream>>>(x, proj_b, (const char*)ws, nullptr, out);
        const int tot4 = 8*128*128*32/4;
        div_kernel<<<(tot4 + 255)/256, 256, 0, stream>>>(out);
    }
}